// Round 14
// baseline (245.964 us; speedup 1.0000x reference)
//
#include <hip/hip_runtime.h>
#include <stdint.h>

#define BB 32
#define CC 2048
#define NPIX 49
#define KPAD 64
#define K9 18432

typedef __bf16 bf16;
typedef __bf16 bf16x2 __attribute__((ext_vector_type(2)));
typedef __bf16 bf16x4 __attribute__((ext_vector_type(4)));
typedef __bf16 bf16x8 __attribute__((ext_vector_type(8)));
typedef float f32x4 __attribute__((ext_vector_type(4)));
typedef uint32_t u32x4 __attribute__((ext_vector_type(4)));

#define MFMA(a,b,c) __builtin_amdgcn_mfma_f32_16x16x32_bf16(a,b,c,0,0,0)
#define GLOAD_LDS(g, l) __builtin_amdgcn_global_load_lds( \
    (const __attribute__((address_space(1))) void*)(g),   \
    (__attribute__((address_space(3))) void*)(l), 16, 0, 0)

// ---------- fused prep: x -> xb [B][C][64] AND xbT [B][64][C] (reads x once) ----------
__global__ void prep_fused_kernel(const float* __restrict__ x,
                                  bf16* __restrict__ xb, bf16* __restrict__ xbT) {
    __shared__ float xt[6272];   // 128*49
    const int tid = threadIdx.x;
    const int b = blockIdx.x >> 4, cb = blockIdx.x & 15;
    const float* src = x + ((size_t)(b * 2048 + cb * 128)) * 49;
#pragma unroll
    for (int i = 0; i < 25; i++) {
        int idx = i * 256 + tid;
        if (idx < 6272) xt[idx] = src[idx];
    }
    __syncthreads();
    {
        const int r = tid >> 1, h = tid & 1;
        bf16* dst = xb + ((size_t)(b * 2048 + cb * 128 + r)) * 64 + h * 32;
        const float* row = &xt[r * 49];
#pragma unroll
        for (int v = 0; v < 4; v++) {
            bf16x8 o;
#pragma unroll
            for (int e = 0; e < 8; e++) {
                int n = h * 32 + v * 8 + e;
                o[e] = (bf16)(n < 49 ? row[n] : 0.f);
            }
            *(bf16x8*)(dst + v * 8) = o;
        }
    }
    {
        const int n = tid >> 2, q = tid & 3;
        bf16* dst = xbT + ((size_t)b * 64 + n) * 2048 + cb * 128 + q * 32;
#pragma unroll
        for (int v = 0; v < 4; v++) {
            bf16x8 o;
#pragma unroll
            for (int e = 0; e < 8; e++) {
                int cl = q * 32 + v * 8 + e;
                o[e] = (bf16)(n < 49 ? xt[cl * 49 + n] : 0.f);
            }
            *(bf16x8*)(dst + v * 8) = o;
        }
    }
}

// ---------- Winograd weight transform: cw [co][ci][3][3] f32 -> Uw bf16 [16][co][ci] ----------
// U = G g G^T, G = [[1,0,0],[.5,.5,.5],[.5,-.5,.5],[0,0,1]]
__global__ void castw_wino_kernel(const float* __restrict__ cw, bf16* __restrict__ Uw) {
    uint32_t t = blockIdx.x * 256u + threadIdx.x;   // 2048*512
    uint32_t q = t & 511u, co = t >> 9;
    uint32_t ci0 = q * 4u;
    const f32x4* src4 = (const f32x4*)(cw + ((size_t)co * 2048u + ci0) * 9u);
    float g[36];
#pragma unroll
    for (int m = 0; m < 9; m++) {
        f32x4 t4 = src4[m];
#pragma unroll
        for (int e = 0; e < 4; e++) g[m * 4 + e] = t4[e];
    }
    float u[16][4];
#pragma unroll
    for (int c4 = 0; c4 < 4; c4++) {
        const float* gg = g + c4 * 9;
        float tr[4][3];
#pragma unroll
        for (int col = 0; col < 3; col++) {
            float a0 = gg[col], a1 = gg[3 + col], a2 = gg[6 + col];
            tr[0][col] = a0;
            tr[1][col] = 0.5f * (a0 + a1 + a2);
            tr[2][col] = 0.5f * (a0 - a1 + a2);
            tr[3][col] = a2;
        }
#pragma unroll
        for (int r = 0; r < 4; r++) {
            u[r * 4 + 0][c4] = tr[r][0];
            u[r * 4 + 1][c4] = 0.5f * (tr[r][0] + tr[r][1] + tr[r][2]);
            u[r * 4 + 2][c4] = 0.5f * (tr[r][0] - tr[r][1] + tr[r][2]);
            u[r * 4 + 3][c4] = tr[r][2];
        }
    }
#pragma unroll
    for (int e = 0; e < 16; e++) {
        bf16x4 o;
        o[0] = (bf16)u[e][0]; o[1] = (bf16)u[e][1];
        o[2] = (bf16)u[e][2]; o[3] = (bf16)u[e][3];
        *(bf16x4*)(Uw + (size_t)e * 4194304u + (size_t)co * 2048u + ci0) = o;
    }
}

// ---------- fused bilinear -> softmax -> Y (R13, unchanged; halo-zero folded) ----------
__global__ __launch_bounds__(512, 2) void attn_kernel(
    const bf16* __restrict__ xb, const bf16* __restrict__ xbT, bf16* __restrict__ YpT)
{
    __shared__ __align__(16) char smem[67584];
    bf16* Ktile = (bf16*)smem;
    bf16* Vtile = (bf16*)(smem + 16384);
    bf16 (*Plds)[16][136] = reinterpret_cast<bf16(*)[16][136]>(smem + 32768);
    bf16 (*Tlds)[132] = reinterpret_cast<bf16(*)[132]>(smem);

    const int tid = threadIdx.x;
    const int w = tid >> 6, l = tid & 63;
    const int lhi = l >> 4, llo = l & 15;
    const uint32_t g = blockIdx.x;
    const int xcd = g & 7, inner = g >> 3;
    const int b = xcd + (inner >> 4) * 8;
    const int cblk = inner & 15;
    const int c0 = cblk * 128 + w * 16;
    const bf16* xbB = xb + (size_t)b * CC * KPAD;
    const bf16* xbTB = xbT + (size_t)b * KPAD * CC;

    {
        int h = tid >> 4, c16 = tid & 15;
        int row;
        if (h < 9) row = h;
        else if (h < 18) row = 63 + h;
        else { int p = h - 18; row = 9 * ((p >> 1) + 1) + (p & 1) * 8; }
        u32x4 z4 = {0, 0, 0, 0};
        *(u32x4*)(YpT + ((size_t)b * 81 + row) * CC + cblk * 128 + c16 * 8) = z4;
    }

    bf16x8 aQ[2];
#pragma unroll
    for (int kk = 0; kk < 2; kk++)
        aQ[kk] = *(const bf16x8*)(xbB + (uint32_t)(c0 + llo) * KPAD + kk * 32 + lhi * 8);

    const uint32_t rowK = tid >> 3;
    const uint32_t srcKoff = (uint32_t)(((tid & 7u) ^ (rowK & 7u)) << 3);
    const bf16* kSrc = xbB + (size_t)rowK * KPAD + srcKoff;
    const uint32_t rowV = tid >> 4;
    const uint32_t srcVoff = (uint32_t)(((tid & 15u) ^ (rowV & 7u)) << 3);
    const bf16* vSrc = xbTB + (size_t)rowV * CC + srcVoff;

    f32x4 accY[4];
#pragma unroll
    for (int nf = 0; nf < 4; nf++) accY[nf] = (f32x4){0, 0, 0, 0};
    float rowsum[4] = {};

    const float kES = -0.029442756956917622f;

    for (int dt = 0; dt < 16; dt++) {
        const int d0 = dt * 128;
#pragma unroll
        for (int i = 0; i < 2; i++) {
            GLOAD_LDS(kSrc + (size_t)(d0 + i * 64) * KPAD, (char*)Ktile + i * 8192 + tid * 16);
            GLOAD_LDS(vSrc + d0 + (size_t)i * 32 * CC,     (char*)Vtile + i * 8192 + tid * 16);
        }
        __syncthreads();

        f32x4 accS[8];
#pragma unroll
        for (int df = 0; df < 8; df++) accS[df] = (f32x4){0, 0, 0, 0};
#pragma unroll
        for (int kk = 0; kk < 2; kk++) {
#pragma unroll
            for (int df = 0; df < 8; df++) {
                uint32_t r = (uint32_t)(df * 16 + llo);
                bf16x8 bK = *(const bf16x8*)((const char*)Ktile + r * 128u +
                                             ((((uint32_t)(kk * 4 + lhi)) ^ (r & 7u)) << 4));
                accS[df] = MFMA(aQ[kk], bK, accS[df]);
            }
        }
#pragma unroll
        for (int df = 0; df < 8; df++)
#pragma unroll
            for (int r = 0; r < 4; r++) {
                float p = __builtin_amdgcn_exp2f(accS[df][r] * kES);
                rowsum[r] += p;
                Plds[w][lhi * 4 + r][df * 16 + llo] = (bf16)p;
            }
#pragma unroll
        for (int kk2 = 0; kk2 < 4; kk2++) {
            bf16x8 aP = *(const bf16x8*)&Plds[w][llo][kk2 * 32 + lhi * 8];
#pragma unroll
            for (int nf = 0; nf < 4; nf++) {
                uint32_t r = (uint32_t)(nf * 16 + llo);
                bf16x8 bV = *(const bf16x8*)((const char*)Vtile + r * 256u +
                                             ((((uint32_t)(kk2 * 4 + lhi)) ^ (r & 7u)) << 4));
                accY[nf] = MFMA(aP, bV, accY[nf]);
            }
        }
        __syncthreads();
    }
#pragma unroll
    for (int r = 0; r < 4; r++) {
        float s = rowsum[r];
        s += __shfl_xor(s, 1);
        s += __shfl_xor(s, 2);
        s += __shfl_xor(s, 4);
        s += __shfl_xor(s, 8);
        rowsum[r] = 1.0f / s;
    }
    __syncthreads();
#pragma unroll
    for (int nf = 0; nf < 4; nf++)
#pragma unroll
        for (int r = 0; r < 4; r++) {
            int n = nf * 16 + llo;
            int cl = w * 16 + lhi * 4 + r;
            Tlds[n][cl] = (bf16)(accY[nf][r] * rowsum[r]);
        }
    __syncthreads();
#pragma unroll
    for (int rr = 0; rr < 7; rr++) {
        int row = rr * 8 + w;
        if (row < NPIX) {
            int i = row / 7, j = row % 7;
            int sp = (i + 1) * 9 + (j + 1);
            int col2 = tid & 63;
            uint32_t val = *(const uint32_t*)&Tlds[row][col2 * 2];
            *(uint32_t*)(YpT + ((size_t)b * 81 + sp) * CC + cblk * 128 + col2 * 2) = val;
        }
    }
}

// ---------- Winograd input transform: YpT [b][81][c] -> Ux bf16 [16][512][c] ----------
// V = B^T d B; input 4x4 tile rows sp=(2ti+di, 2tj+dj) of the padded 9x9 (halos zero).
// Row/col index 9 (clamped to 8) only feeds dropped outputs.
__global__ void wino_in_kernel(const bf16* __restrict__ YpT, bf16* __restrict__ Ux) {
    const int n = blockIdx.x;                 // 512 = b*16 + ti*4 + tj
    const int b = n >> 4, t = n & 15, ti = t >> 2, tj = t & 3;
    const int c0 = threadIdx.x * 4;           // 512 threads x 4 channels
    float d[4][4][4];
#pragma unroll
    for (int di = 0; di < 4; di++) {
        int spi = 2 * ti + di; if (spi > 8) spi = 8;
#pragma unroll
        for (int dj = 0; dj < 4; dj++) {
            int spj = 2 * tj + dj; if (spj > 8) spj = 8;
            bf16x4 v = *(const bf16x4*)(YpT + ((size_t)b * 81 + spi * 9 + spj) * 2048 + c0);
#pragma unroll
            for (int k = 0; k < 4; k++) d[di][dj][k] = (float)v[k];
        }
    }
    float R[4][4][4];
#pragma unroll
    for (int dj = 0; dj < 4; dj++)
#pragma unroll
        for (int k = 0; k < 4; k++) {
            R[0][dj][k] = d[0][dj][k] - d[2][dj][k];
            R[1][dj][k] = d[1][dj][k] + d[2][dj][k];
            R[2][dj][k] = d[2][dj][k] - d[1][dj][k];
            R[3][dj][k] = d[1][dj][k] - d[3][dj][k];
        }
#pragma unroll
    for (int r = 0; r < 4; r++) {
#pragma unroll
        for (int k = 0; k < 4; k++) {
            float v0 = R[r][0][k] - R[r][2][k];
            float v1 = R[r][1][k] + R[r][2][k];
            float v2 = R[r][2][k] - R[r][1][k];
            float v3 = R[r][1][k] - R[r][3][k];
            R[r][0][k] = v0; R[r][1][k] = v1; R[r][2][k] = v2; R[r][3][k] = v3;
        }
#pragma unroll
        for (int cc = 0; cc < 4; cc++) {
            bf16x4 o;
#pragma unroll
            for (int k = 0; k < 4; k++) o[k] = (bf16)R[r][cc][k];
            *(bf16x4*)(Ux + (size_t)(r * 4 + cc) * 1048576u + (size_t)n * 2048 + c0) = o;
        }
    }
}

// ---------- Winograd GEMM: 16x [ C[n 512][co 2048] = Ux[e] x Uw[e]^T ], K=2048 ----------
// 256 blocks = 16e x (2mt x 8nt), 1/CU; R11-verified phase schedule (no tap, no guard).
#define CONV_BARRIER() do { __builtin_amdgcn_sched_barrier(0); \
    __builtin_amdgcn_s_barrier(); __builtin_amdgcn_sched_barrier(0); } while (0)
#define CONV_VMW(n) asm volatile("s_waitcnt vmcnt(" #n ")" ::: "memory")

#define WSTAGE(bufOff, t, kh) do {                                             \
    uint32_t kA_ = (uint32_t)(t) * 64u + (uint32_t)(kh) * 32u;                 \
    _Pragma("unroll")                                                          \
    for (int i_ = 0; i_ < 2; i_++) {                                           \
        GLOAD_LDS(srcA[i_] + kA_,                                              \
                  smem + (bufOff) + (kh) * 16384 + i_ * 8192 + tid * 16);      \
        GLOAD_LDS(srcB[i_] + kA_,                                              \
                  smem + (bufOff) + 32768 + (kh) * 16384 + i_ * 8192 + tid * 16); \
    }                                                                          \
} while (0)

#define CONV_PHASE(bufOff, kk, GATE, STAGE_STMT) do {                          \
    CONV_VMW(GATE);                                                            \
    CONV_BARRIER();                                                            \
    bf16x8 af[8], bfr[4];                                                      \
    _Pragma("unroll")                                                          \
    for (int f = 0; f < 8; f++)                                                \
        af[f] = *(const bf16x8*)(smem + (bufOff) + (kk) * 16384 + offA[f]);    \
    _Pragma("unroll")                                                          \
    for (int f = 0; f < 4; f++)                                                \
        bfr[f] = *(const bf16x8*)(smem + (bufOff) + 32768 + (kk) * 16384 + offB[f]); \
    STAGE_STMT;                                                                \
    asm volatile("s_waitcnt lgkmcnt(0)" ::: "memory");                         \
    __builtin_amdgcn_sched_barrier(0);                                         \
    __builtin_amdgcn_s_setprio(1);                                             \
    _Pragma("unroll")                                                          \
    for (int fm = 0; fm < 8; fm++)                                             \
        _Pragma("unroll")                                                      \
        for (int fn = 0; fn < 4; fn++)                                         \
            acc[fm][fn] = MFMA(af[fm], bfr[fn], acc[fm][fn]);                  \
    __builtin_amdgcn_s_setprio(0);                                             \
    __builtin_amdgcn_sched_barrier(0);                                         \
} while (0)

__global__ __launch_bounds__(512, 2) void wino_gemm_kernel(
    const bf16* __restrict__ Ux, const bf16* __restrict__ Uw, bf16* __restrict__ Vt)
{
    extern __shared__ __align__(16) char smem[];
    const int tid = threadIdx.x;
    const int w = tid >> 6, l = tid & 63;
    const int lhi = l >> 4, llo = l & 15;
    const int wm = w >> 2, wn = w & 3;           // wave owns 128 n x 64 co

    uint32_t g = blockIdx.x;
    uint32_t xcd = g & 7u, inner = g >> 3;       // inner in [0,32)
    uint32_t e = xcd * 2u + (inner >> 4);        // 2 e-planes per XCD
    uint32_t sub = inner & 15u;
    uint32_t mt = sub >> 3, nt = sub & 7u;

    uint32_t rowLoc = tid >> 2;                  // [0,128)
    uint32_t slot = tid & 3u;
    const bf16* srcA[2];
    const bf16* srcB[2];
#pragma unroll
    for (int i = 0; i < 2; i++) {
        uint32_t row = (uint32_t)i * 128u + rowLoc;
        uint32_t swz = (uint32_t)((slot ^ ((row >> 1) & 3u)) << 3);
        srcA[i] = Ux + (size_t)e * 1048576u + (size_t)(mt * 256u + row) * 2048u + swz;
        srcB[i] = Uw + (size_t)e * 4194304u + (size_t)(nt * 256u + row) * 2048u + swz;
    }

    uint32_t offA[8], offB[4];
#pragma unroll
    for (int f = 0; f < 8; f++) {
        uint32_t r = (uint32_t)(wm * 128 + f * 16 + llo);
        offA[f] = r * 64u + (uint32_t)(((uint32_t)lhi ^ ((r >> 1) & 3u)) << 4);
    }
#pragma unroll
    for (int f = 0; f < 4; f++) {
        uint32_t r = (uint32_t)(wn * 64 + f * 16 + llo);
        offB[f] = r * 64u + (uint32_t)(((uint32_t)lhi ^ ((r >> 1) & 3u)) << 4);
    }

    f32x4 acc[8][4];
#pragma unroll
    for (int fm = 0; fm < 8; fm++)
#pragma unroll
        for (int fn = 0; fn < 4; fn++) acc[fm][fn] = (f32x4){0, 0, 0, 0};

    // prologue: T0.k0, T0.k1 -> buf0; T1.k0 -> buf1
    WSTAGE(0, 0, 0);
    WSTAGE(0, 0, 1);
    WSTAGE(65536, 1, 0);

    for (int it = 0; it < 15; ++it) {
        const int t0 = it * 2;
        CONV_PHASE(0,     0, 8, WSTAGE(65536, t0 + 1, 1));
        CONV_PHASE(0,     1, 8, WSTAGE(0,     t0 + 2, 0));
        CONV_PHASE(65536, 0, 8, WSTAGE(0,     t0 + 2, 1));
        CONV_PHASE(65536, 1, 8, WSTAGE(65536, t0 + 3, 0));
    }
    // peeled final pair (tiles 30 buf0, 31 buf1); gates 8,8,4,0
    CONV_PHASE(0,     0, 8, WSTAGE(65536, 31, 1));
    CONV_PHASE(0,     1, 8, (void)0);
    CONV_PHASE(65536, 0, 4, (void)0);
    CONV_PHASE(65536, 1, 0, (void)0);

    bf16* pz = Vt + (size_t)e * 1048576u;
    uint32_t n0 = mt * 256u + (uint32_t)(wm * 128 + lhi * 4);
    uint32_t co0 = nt * 256u + (uint32_t)(wn * 64 + llo);
#pragma unroll
    for (int fm = 0; fm < 8; fm++)
#pragma unroll
        for (int fn = 0; fn < 4; fn++)
#pragma unroll
            for (int r = 0; r < 4; r++)
                pz[(size_t)(n0 + fm * 16u + r) * 2048u + (co0 + fn * 16u)] =
                    (bf16)acc[fm][fn][r];
}

// ---------- Winograd output transform + bias + residual ----------
// out[b][c][i*7+j] = (A^T M A)(oi,oj) + cb[c] + x; M[e] = Vt[e][b*16+t][c]
__global__ void wino_out_kernel(const bf16* __restrict__ Vt, const float* __restrict__ x,
                                const float* __restrict__ cb, float* __restrict__ out)
{
    __shared__ float Ml[16][16][33];   // [e][tile][c 32 +pad]
    __shared__ float Ol[32][50];       // [c][p]
    __shared__ float cbl[32];
    const int tid = threadIdx.x;
    const int b = blockIdx.x >> 6, cg = blockIdx.x & 63;
    const int c0 = cg * 32;

    {   // phase 1: load 16e x 16t x 32c
        int e = tid >> 4, t = tid & 15;
        const bf16* src = Vt + ((size_t)e * 512 + b * 16 + t) * 2048 + c0;
#pragma unroll
        for (int v = 0; v < 4; v++) {
            bf16x8 vv = *(const bf16x8*)(src + v * 8);
#pragma unroll
            for (int k = 0; k < 8; k++) Ml[e][t][v * 8 + k] = (float)vv[k];
        }
    }
    if (tid < 32) cbl[tid] = cb[c0 + tid];
    __syncthreads();

    {   // phase 2: per (tile, c-pair) compute 2x2 outputs
        int t = tid & 15, cp = tid >> 4;
        int ti = t >> 2, tj = t & 3;
#pragma unroll
        for (int cc2 = 0; cc2 < 2; cc2++) {
            int cc = cp * 2 + cc2;
            float M[16];
#pragma unroll
            for (int e = 0; e < 16; e++) M[e] = Ml[e][t][cc];
            float s0[4], s1[4];
#pragma unroll
            for (int col = 0; col < 4; col++) {
                s0[col] = M[col] + M[4 + col] + M[8 + col];
                s1[col] = M[4 + col] - M[8 + col] - M[12 + col];
            }
            float y00 = s0[0] + s0[1] + s0[2];
            float y01 = s0[1] - s0[2] - s0[3];
            float y10 = s1[0] + s1[1] + s1[2];
            float y11 = s1[1] - s1[2] - s1[3];
            int i0 = 2 * ti, j0 = 2 * tj;
            Ol[cc][i0 * 7 + j0] = y00;
            if (j0 + 1 < 7) Ol[cc][i0 * 7 + j0 + 1] = y01;
            if (i0 + 1 < 7) Ol[cc][(i0 + 1) * 7 + j0] = y10;
            if (i0 + 1 < 7 && j0 + 1 < 7) Ol[cc][(i0 + 1) * 7 + j0 + 1] = y11;
        }
    }
    __syncthreads();

    {   // phase 3: out span [b][c0..c0+31][0..48] contiguous
        const float* xs = x + ((size_t)b * 2048 + c0) * 49;
        float* os = out + ((size_t)b * 2048 + c0) * 49;
        for (int k = tid; k < 1568; k += 256) {
            int c = k / 49, p = k - c * 49;
            os[k] = Ol[c][p] + cbl[c] + xs[k];
        }
    }
}

extern "C" void kernel_launch(void* const* d_in, const int* in_sizes, int n_in,
                              void* d_out, int out_size, void* d_ws, size_t ws_size,
                              hipStream_t stream) {
    (void)in_sizes; (void)n_in; (void)out_size; (void)ws_size;
    const float* x = (const float*)d_in[0];
    const float* cw = (const float*)d_in[1];
    const float* cb = (const float*)d_in[2];
    float* out = (float*)d_out;
    char* ws = (char*)d_ws;

    // layout (peak 212.1 MB):
    // [0]          Ux  33,554,432  (first 16.8 MB doubles as xb+xbT during prep/attn)
    // [33,554,432] YpT 10,747,904
    // [44,302,336] Uw 134,217,728
    // [178,520,064] Vt 33,554,432   -> end 212,074,496
    bf16* xb  = (bf16*)(ws);
    bf16* xbT = (bf16*)(ws + 8388608);
    bf16* Ux  = (bf16*)(ws);
    bf16* YpT = (bf16*)(ws + 33554432);
    bf16* Uw  = (bf16*)(ws + 44302336);
    bf16* Vt  = (bf16*)(ws + 178520064);

    hipFuncSetAttribute((const void*)wino_gemm_kernel,
                        hipFuncAttributeMaxDynamicSharedMemorySize, 131072);

    prep_fused_kernel<<<512, 256, 0, stream>>>(x, xb, xbT);
    castw_wino_kernel<<<4096, 256, 0, stream>>>(cw, Uw);
    attn_kernel<<<512, 512, 0, stream>>>(xb, xbT, YpT);
    wino_in_kernel<<<512, 512, 0, stream>>>(YpT, Ux);
    wino_gemm_kernel<<<256, 512, 131072, stream>>>(Ux, Uw, Vt);
    wino_out_kernel<<<2048, 256, 0, stream>>>(Vt, x, cb, out);
}

// Round 15
// 229.493 us; speedup vs baseline: 1.0718x; 1.0718x over previous
//
#include <hip/hip_runtime.h>
#include <stdint.h>

#define BB 32
#define CC 2048
#define NPIX 49
#define KPAD 64

typedef __bf16 bf16;
typedef __bf16 bf16x4 __attribute__((ext_vector_type(4)));
typedef __bf16 bf16x8 __attribute__((ext_vector_type(8)));
typedef float f32x4 __attribute__((ext_vector_type(4)));
typedef uint32_t u32x4 __attribute__((ext_vector_type(4)));
typedef long i64;

#define MFMA(a,b,c) __builtin_amdgcn_mfma_f32_16x16x32_bf16(a,b,c,0,0,0)
#define MFMA8(a,b,c) __builtin_amdgcn_mfma_f32_16x16x32_fp8_fp8(a,b,c,0,0,0)
#define GLOAD_LDS(g, l) __builtin_amdgcn_global_load_lds( \
    (const __attribute__((address_space(1))) void*)(g),   \
    (__attribute__((address_space(3))) void*)(l), 16, 0, 0)

// ---------- fused prep: x -> xb [B][C][64] AND xbT [B][64][C] (reads x once) ----------
__global__ void prep_fused_kernel(const float* __restrict__ x,
                                  bf16* __restrict__ xb, bf16* __restrict__ xbT) {
    __shared__ float xt[6272];   // 128*49
    const int tid = threadIdx.x;
    const int b = blockIdx.x >> 4, cb = blockIdx.x & 15;
    const float* src = x + ((size_t)(b * 2048 + cb * 128)) * 49;
#pragma unroll
    for (int i = 0; i < 25; i++) {
        int idx = i * 256 + tid;
        if (idx < 6272) xt[idx] = src[idx];
    }
    __syncthreads();
    {
        const int r = tid >> 1, h = tid & 1;
        bf16* dst = xb + ((size_t)(b * 2048 + cb * 128 + r)) * 64 + h * 32;
        const float* row = &xt[r * 49];
#pragma unroll
        for (int v = 0; v < 4; v++) {
            bf16x8 o;
#pragma unroll
            for (int e = 0; e < 8; e++) {
                int n = h * 32 + v * 8 + e;
                o[e] = (bf16)(n < 49 ? row[n] : 0.f);
            }
            *(bf16x8*)(dst + v * 8) = o;
        }
    }
    {
        const int n = tid >> 2, q = tid & 3;
        bf16* dst = xbT + ((size_t)b * 64 + n) * 2048 + cb * 128 + q * 32;
#pragma unroll
        for (int v = 0; v < 4; v++) {
            bf16x8 o;
#pragma unroll
            for (int e = 0; e < 8; e++) {
                int cl = q * 32 + v * 8 + e;
                o[e] = (bf16)(n < 49 ? xt[cl * 49 + n] : 0.f);
            }
            *(bf16x8*)(dst + v * 8) = o;
        }
    }
}

// ---------- Winograd weight transform -> Uw fp8 e4m3 [16][co][ci], scaled x16 ----------
__global__ void castw_wino_kernel(const float* __restrict__ cw, uint8_t* __restrict__ Uw) {
    uint32_t t = blockIdx.x * 256u + threadIdx.x;   // 2048*512
    uint32_t q = t & 511u, co = t >> 9;
    uint32_t ci0 = q * 4u;
    const f32x4* src4 = (const f32x4*)(cw + ((size_t)co * 2048u + ci0) * 9u);
    float g[36];
#pragma unroll
    for (int m = 0; m < 9; m++) {
        f32x4 t4 = src4[m];
#pragma unroll
        for (int e = 0; e < 4; e++) g[m * 4 + e] = t4[e];
    }
    float u[16][4];
#pragma unroll
    for (int c4 = 0; c4 < 4; c4++) {
        const float* gg = g + c4 * 9;
        float tr[4][3];
#pragma unroll
        for (int col = 0; col < 3; col++) {
            float a0 = gg[col], a1 = gg[3 + col], a2 = gg[6 + col];
            tr[0][col] = a0;
            tr[1][col] = 0.5f * (a0 + a1 + a2);
            tr[2][col] = 0.5f * (a0 - a1 + a2);
            tr[3][col] = a2;
        }
#pragma unroll
        for (int r = 0; r < 4; r++) {
            u[r * 4 + 0][c4] = tr[r][0];
            u[r * 4 + 1][c4] = 0.5f * (tr[r][0] + tr[r][1] + tr[r][2]);
            u[r * 4 + 2][c4] = 0.5f * (tr[r][0] - tr[r][1] + tr[r][2]);
            u[r * 4 + 3][c4] = tr[r][2];
        }
    }
#pragma unroll
    for (int e = 0; e < 16; e++) {
        int p = __builtin_amdgcn_cvt_pk_fp8_f32(u[e][0] * 16.f, u[e][1] * 16.f, 0, false);
        p = __builtin_amdgcn_cvt_pk_fp8_f32(u[e][2] * 16.f, u[e][3] * 16.f, p, true);
        *(uint32_t*)(Uw + (size_t)e * 4194304u + (size_t)co * 2048u + ci0) = (uint32_t)p;
    }
}

// ---------- fused bilinear -> softmax -> Y (R13, unchanged; halo-zero folded) ----------
__global__ __launch_bounds__(512, 2) void attn_kernel(
    const bf16* __restrict__ xb, const bf16* __restrict__ xbT, bf16* __restrict__ YpT)
{
    __shared__ __align__(16) char smem[67584];
    bf16* Ktile = (bf16*)smem;
    bf16* Vtile = (bf16*)(smem + 16384);
    bf16 (*Plds)[16][136] = reinterpret_cast<bf16(*)[16][136]>(smem + 32768);
    bf16 (*Tlds)[132] = reinterpret_cast<bf16(*)[132]>(smem);

    const int tid = threadIdx.x;
    const int w = tid >> 6, l = tid & 63;
    const int lhi = l >> 4, llo = l & 15;
    const uint32_t g = blockIdx.x;
    const int xcd = g & 7, inner = g >> 3;
    const int b = xcd + (inner >> 4) * 8;
    const int cblk = inner & 15;
    const int c0 = cblk * 128 + w * 16;
    const bf16* xbB = xb + (size_t)b * CC * KPAD;
    const bf16* xbTB = xbT + (size_t)b * KPAD * CC;

    {
        int h = tid >> 4, c16 = tid & 15;
        int row;
        if (h < 9) row = h;
        else if (h < 18) row = 63 + h;
        else { int p = h - 18; row = 9 * ((p >> 1) + 1) + (p & 1) * 8; }
        u32x4 z4 = {0, 0, 0, 0};
        *(u32x4*)(YpT + ((size_t)b * 81 + row) * CC + cblk * 128 + c16 * 8) = z4;
    }

    bf16x8 aQ[2];
#pragma unroll
    for (int kk = 0; kk < 2; kk++)
        aQ[kk] = *(const bf16x8*)(xbB + (uint32_t)(c0 + llo) * KPAD + kk * 32 + lhi * 8);

    const uint32_t rowK = tid >> 3;
    const uint32_t srcKoff = (uint32_t)(((tid & 7u) ^ (rowK & 7u)) << 3);
    const bf16* kSrc = xbB + (size_t)rowK * KPAD + srcKoff;
    const uint32_t rowV = tid >> 4;
    const uint32_t srcVoff = (uint32_t)(((tid & 15u) ^ (rowV & 7u)) << 3);
    const bf16* vSrc = xbTB + (size_t)rowV * CC + srcVoff;

    f32x4 accY[4];
#pragma unroll
    for (int nf = 0; nf < 4; nf++) accY[nf] = (f32x4){0, 0, 0, 0};
    float rowsum[4] = {};

    const float kES = -0.029442756956917622f;

    for (int dt = 0; dt < 16; dt++) {
        const int d0 = dt * 128;
#pragma unroll
        for (int i = 0; i < 2; i++) {
            GLOAD_LDS(kSrc + (size_t)(d0 + i * 64) * KPAD, (char*)Ktile + i * 8192 + tid * 16);
            GLOAD_LDS(vSrc + d0 + (size_t)i * 32 * CC,     (char*)Vtile + i * 8192 + tid * 16);
        }
        __syncthreads();

        f32x4 accS[8];
#pragma unroll
        for (int df = 0; df < 8; df++) accS[df] = (f32x4){0, 0, 0, 0};
#pragma unroll
        for (int kk = 0; kk < 2; kk++) {
#pragma unroll
            for (int df = 0; df < 8; df++) {
                uint32_t r = (uint32_t)(df * 16 + llo);
                bf16x8 bK = *(const bf16x8*)((const char*)Ktile + r * 128u +
                                             ((((uint32_t)(kk * 4 + lhi)) ^ (r & 7u)) << 4));
                accS[df] = MFMA(aQ[kk], bK, accS[df]);
            }
        }
#pragma unroll
        for (int df = 0; df < 8; df++)
#pragma unroll
            for (int r = 0; r < 4; r++) {
                float p = __builtin_amdgcn_exp2f(accS[df][r] * kES);
                rowsum[r] += p;
                Plds[w][lhi * 4 + r][df * 16 + llo] = (bf16)p;
            }
#pragma unroll
        for (int kk2 = 0; kk2 < 4; kk2++) {
            bf16x8 aP = *(const bf16x8*)&Plds[w][llo][kk2 * 32 + lhi * 8];
#pragma unroll
            for (int nf = 0; nf < 4; nf++) {
                uint32_t r = (uint32_t)(nf * 16 + llo);
                bf16x8 bV = *(const bf16x8*)((const char*)Vtile + r * 256u +
                                             ((((uint32_t)(kk2 * 4 + lhi)) ^ (r & 7u)) << 4));
                accY[nf] = MFMA(aP, bV, accY[nf]);
            }
        }
        __syncthreads();
    }
#pragma unroll
    for (int r = 0; r < 4; r++) {
        float s = rowsum[r];
        s += __shfl_xor(s, 1);
        s += __shfl_xor(s, 2);
        s += __shfl_xor(s, 4);
        s += __shfl_xor(s, 8);
        rowsum[r] = 1.0f / s;
    }
    __syncthreads();
#pragma unroll
    for (int nf = 0; nf < 4; nf++)
#pragma unroll
        for (int r = 0; r < 4; r++) {
            int n = nf * 16 + llo;
            int cl = w * 16 + lhi * 4 + r;
            Tlds[n][cl] = (bf16)(accY[nf][r] * rowsum[r]);
        }
    __syncthreads();
#pragma unroll
    for (int rr = 0; rr < 7; rr++) {
        int row = rr * 8 + w;
        if (row < NPIX) {
            int i = row / 7, j = row % 7;
            int sp = (i + 1) * 9 + (j + 1);
            int col2 = tid & 63;
            uint32_t val = *(const uint32_t*)&Tlds[row][col2 * 2];
            *(uint32_t*)(YpT + ((size_t)b * 81 + sp) * CC + cblk * 128 + col2 * 2) = val;
        }
    }
}

// ---------- Winograd input transform: YpT bf16 -> Ux fp8 [16][512][c], scaled x4 ----------
__global__ void wino_in_kernel(const bf16* __restrict__ YpT, uint8_t* __restrict__ Ux) {
    const int n = blockIdx.x;                 // 512 = b*16 + ti*4 + tj
    const int b = n >> 4, t = n & 15, ti = t >> 2, tj = t & 3;
    const int c0 = threadIdx.x * 4;
    float d[4][4][4];
#pragma unroll
    for (int di = 0; di < 4; di++) {
        int spi = 2 * ti + di; if (spi > 8) spi = 8;
#pragma unroll
        for (int dj = 0; dj < 4; dj++) {
            int spj = 2 * tj + dj; if (spj > 8) spj = 8;
            bf16x4 v = *(const bf16x4*)(YpT + ((size_t)b * 81 + spi * 9 + spj) * 2048 + c0);
#pragma unroll
            for (int k = 0; k < 4; k++) d[di][dj][k] = (float)v[k];
        }
    }
    float R[4][4][4];
#pragma unroll
    for (int dj = 0; dj < 4; dj++)
#pragma unroll
        for (int k = 0; k < 4; k++) {
            R[0][dj][k] = d[0][dj][k] - d[2][dj][k];
            R[1][dj][k] = d[1][dj][k] + d[2][dj][k];
            R[2][dj][k] = d[2][dj][k] - d[1][dj][k];
            R[3][dj][k] = d[1][dj][k] - d[3][dj][k];
        }
#pragma unroll
    for (int r = 0; r < 4; r++) {
#pragma unroll
        for (int k = 0; k < 4; k++) {
            float v0 = R[r][0][k] - R[r][2][k];
            float v1 = R[r][1][k] + R[r][2][k];
            float v2 = R[r][2][k] - R[r][1][k];
            float v3 = R[r][1][k] - R[r][3][k];
            R[r][0][k] = v0; R[r][1][k] = v1; R[r][2][k] = v2; R[r][3][k] = v3;
        }
#pragma unroll
        for (int cc = 0; cc < 4; cc++) {
            int p = __builtin_amdgcn_cvt_pk_fp8_f32(R[r][cc][0] * 4.f, R[r][cc][1] * 4.f, 0, false);
            p = __builtin_amdgcn_cvt_pk_fp8_f32(R[r][cc][2] * 4.f, R[r][cc][3] * 4.f, p, true);
            *(uint32_t*)(Ux + (size_t)(r * 4 + cc) * 1048576u + (size_t)n * 2048 + c0) = (uint32_t)p;
        }
    }
}

// ---------- Winograd GEMM fp8: 16x [ C[n 512][co 2048] = Ux[e] x Uw[e]^T ], K=2048 ----------
// 256 blocks (1/CU); K-tile = 128 fp8 (same 16KB half-tile bytes, same swizzle/gates as R11);
// per phase: 2 k-steps x 32 MFMA (fp8 16x16x32). A/B share the frag k-map -> permutation cancels.
#define CONV_BARRIER() do { __builtin_amdgcn_sched_barrier(0); \
    __builtin_amdgcn_s_barrier(); __builtin_amdgcn_sched_barrier(0); } while (0)
#define CONV_VMW(n) asm volatile("s_waitcnt vmcnt(" #n ")" ::: "memory")

#define WSTAGE(bufOff, t, kh) do {                                             \
    uint32_t kA_ = (uint32_t)(t) * 128u + (uint32_t)(kh) * 64u;                \
    _Pragma("unroll")                                                          \
    for (int i_ = 0; i_ < 2; i_++) {                                           \
        GLOAD_LDS(srcA[i_] + kA_,                                              \
                  smem + (bufOff) + (kh) * 16384 + i_ * 8192 + tid * 16);      \
        GLOAD_LDS(srcB[i_] + kA_,                                              \
                  smem + (bufOff) + 32768 + (kh) * 16384 + i_ * 8192 + tid * 16); \
    }                                                                          \
} while (0)

#define CONV_PHASE(bufOff, kk, GATE, STAGE_STMT) do {                          \
    CONV_VMW(GATE);                                                            \
    CONV_BARRIER();                                                            \
    i64 af[8][2], bfr[4][2];                                                   \
    _Pragma("unroll")                                                          \
    for (int f = 0; f < 8; f++)                                                \
        _Pragma("unroll")                                                      \
        for (int s = 0; s < 2; s++)                                            \
            af[f][s] = *(const i64*)(smem + (bufOff) + (kk) * 16384 + offA[f][s]); \
    _Pragma("unroll")                                                          \
    for (int f = 0; f < 4; f++)                                                \
        _Pragma("unroll")                                                      \
        for (int s = 0; s < 2; s++)                                            \
            bfr[f][s] = *(const i64*)(smem + (bufOff) + 32768 + (kk) * 16384 + offB[f][s]); \
    STAGE_STMT;                                                                \
    asm volatile("s_waitcnt lgkmcnt(0)" ::: "memory");                         \
    __builtin_amdgcn_sched_barrier(0);                                         \
    __builtin_amdgcn_s_setprio(1);                                             \
    _Pragma("unroll")                                                          \
    for (int s = 0; s < 2; s++)                                                \
        _Pragma("unroll")                                                      \
        for (int fm = 0; fm < 8; fm++)                                         \
            _Pragma("unroll")                                                  \
            for (int fn = 0; fn < 4; fn++)                                     \
                acc[fm][fn] = MFMA8(af[fm][s], bfr[fn][s], acc[fm][fn]);       \
    __builtin_amdgcn_s_setprio(0);                                             \
    __builtin_amdgcn_sched_barrier(0);                                         \
} while (0)

__global__ __launch_bounds__(512, 2) void wino_gemm_kernel(
    const uint8_t* __restrict__ Ux, const uint8_t* __restrict__ Uw, bf16* __restrict__ Vt)
{
    extern __shared__ __align__(16) char smem[];
    const int tid = threadIdx.x;
    const int w = tid >> 6, l = tid & 63;
    const int lhi = l >> 4, llo = l & 15;
    const int wm = w >> 2, wn = w & 3;           // wave owns 128 n x 64 co

    uint32_t g = blockIdx.x;
    uint32_t xcd = g & 7u, inner = g >> 3;       // [0,32)
    uint32_t e = xcd * 2u + (inner >> 4);        // 2 e-planes per XCD
    uint32_t sub = inner & 15u;
    uint32_t mt = sub >> 3, nt = sub & 7u;

    // staging source: 16B granule, pre-swizzled slot ^ ((row>>1)&3) (same as R11 in bytes)
    uint32_t rowLoc = tid >> 2;                  // [0,128)
    uint32_t slot = tid & 3u;
    const uint8_t* srcA[2];
    const uint8_t* srcB[2];
#pragma unroll
    for (int i = 0; i < 2; i++) {
        uint32_t row = (uint32_t)i * 128u + rowLoc;
        uint32_t swz = (uint32_t)((slot ^ ((row >> 1) & 3u)) << 4);   // bytes
        srcA[i] = Ux + (size_t)e * 1048576u + (size_t)(mt * 256u + row) * 2048u + swz;
        srcB[i] = Uw + (size_t)e * 4194304u + (size_t)(nt * 256u + row) * 2048u + swz;
    }

    // ds_read b64 offsets: step s, lane lhi -> k-group g=4s+lhi; 16B-slot q=2s+(lhi>>1) ^ swz
    uint32_t offA[8][2], offB[4][2];
#pragma unroll
    for (int f = 0; f < 8; f++) {
        uint32_t r = (uint32_t)(wm * 128 + f * 16 + llo);
#pragma unroll
        for (int s = 0; s < 2; s++) {
            uint32_t q = ((uint32_t)(2 * s + (lhi >> 1))) ^ ((r >> 1) & 3u);
            offA[f][s] = r * 64u + (q << 4) + ((uint32_t)(lhi & 1) << 3);
        }
    }
#pragma unroll
    for (int f = 0; f < 4; f++) {
        uint32_t r = (uint32_t)(wn * 64 + f * 16 + llo);
#pragma unroll
        for (int s = 0; s < 2; s++) {
            uint32_t q = ((uint32_t)(2 * s + (lhi >> 1))) ^ ((r >> 1) & 3u);
            offB[f][s] = r * 64u + (q << 4) + ((uint32_t)(lhi & 1) << 3);
        }
    }

    f32x4 acc[8][4];
#pragma unroll
    for (int fm = 0; fm < 8; fm++)
#pragma unroll
        for (int fn = 0; fn < 4; fn++) acc[fm][fn] = (f32x4){0, 0, 0, 0};

    // prologue: T0.k0, T0.k1 -> buf0; T1.k0 -> buf1
    WSTAGE(0, 0, 0);
    WSTAGE(0, 0, 1);
    WSTAGE(65536, 1, 0);

    for (int it = 0; it < 7; ++it) {
        const int t0 = it * 2;
        CONV_PHASE(0,     0, 8, WSTAGE(65536, t0 + 1, 1));
        CONV_PHASE(0,     1, 8, WSTAGE(0,     t0 + 2, 0));
        CONV_PHASE(65536, 0, 8, WSTAGE(0,     t0 + 2, 1));
        CONV_PHASE(65536, 1, 8, WSTAGE(65536, t0 + 3, 0));
    }
    // peeled final pair (tiles 14 buf0, 15 buf1); gates 8,8,4,0
    CONV_PHASE(0,     0, 8, WSTAGE(65536, 15, 1));
    CONV_PHASE(0,     1, 8, (void)0);
    CONV_PHASE(65536, 0, 4, (void)0);
    CONV_PHASE(65536, 1, 0, (void)0);

    bf16* pz = Vt + (size_t)e * 1048576u;
    uint32_t n0 = mt * 256u + (uint32_t)(wm * 128 + lhi * 4);
    uint32_t co0 = nt * 256u + (uint32_t)(wn * 64 + llo);
#pragma unroll
    for (int fm = 0; fm < 8; fm++)
#pragma unroll
        for (int fn = 0; fn < 4; fn++)
#pragma unroll
            for (int r = 0; r < 4; r++)
                pz[(size_t)(n0 + fm * 16u + r) * 2048u + (co0 + fn * 16u)] =
                    (bf16)acc[fm][fn][r];
}

// ---------- Winograd output transform + bias + residual (M scaled by 1/64) ----------
__global__ void wino_out_kernel(const bf16* __restrict__ Vt, const float* __restrict__ x,
                                const float* __restrict__ cb, float* __restrict__ out)
{
    __shared__ float Ml[16][16][33];
    __shared__ float Ol[32][50];
    __shared__ float cbl[32];
    const int tid = threadIdx.x;
    const int b = blockIdx.x >> 6, cg = blockIdx.x & 63;
    const int c0 = cg * 32;

    {
        int e = tid >> 4, t = tid & 15;
        const bf16* src = Vt + ((size_t)e * 512 + b * 16 + t) * 2048 + c0;
#pragma unroll
        for (int v = 0; v < 4; v++) {
            bf16x8 vv = *(const bf16x8*)(src + v * 8);
#pragma unroll
            for (int k = 0; k < 8; k++) Ml[e][t][v * 8 + k] = (float)vv[k] * 0.015625f;
        }
    }
    if (tid < 32) cbl[tid] = cb[c0 + tid];
    __syncthreads();

    {
        int t = tid & 15, cp = tid >> 4;
        int ti = t >> 2, tj = t & 3;
#pragma unroll
        for (int cc2 = 0; cc2 < 2; cc2++) {
            int cc = cp * 2 + cc2;
            float M[16];
#pragma unroll
            for (int e = 0; e < 16; e++) M[e] = Ml[e][t][cc];
            float s0[4], s1[4];
#pragma unroll
            for (int col = 0; col < 4; col++) {
                s0[col] = M[col] + M[4 + col] + M[8 + col];
                s1[col] = M[4 + col] - M[8 + col] - M[12 + col];
            }
            float y00 = s0[0] + s0[1] + s0[2];
            float y01 = s0[1] - s0[2] - s0[3];
            float y10 = s1[0] + s1[1] + s1[2];
            float y11 = s1[1] - s1[2] - s1[3];
            int i0 = 2 * ti, j0 = 2 * tj;
            Ol[cc][i0 * 7 + j0] = y00;
            if (j0 + 1 < 7) Ol[cc][i0 * 7 + j0 + 1] = y01;
            if (i0 + 1 < 7) Ol[cc][(i0 + 1) * 7 + j0] = y10;
            if (i0 + 1 < 7 && j0 + 1 < 7) Ol[cc][(i0 + 1) * 7 + j0 + 1] = y11;
        }
    }
    __syncthreads();

    {
        const float* xs = x + ((size_t)b * 2048 + c0) * 49;
        float* os = out + ((size_t)b * 2048 + c0) * 49;
        for (int k = tid; k < 1568; k += 256) {
            int c = k / 49, p = k - c * 49;
            os[k] = Ol[c][p] + cbl[c] + xs[k];
        }
    }
}

extern "C" void kernel_launch(void* const* d_in, const int* in_sizes, int n_in,
                              void* d_out, int out_size, void* d_ws, size_t ws_size,
                              hipStream_t stream) {
    (void)in_sizes; (void)n_in; (void)out_size; (void)ws_size;
    const float* x = (const float*)d_in[0];
    const float* cw = (const float*)d_in[1];
    const float* cb = (const float*)d_in[2];
    float* out = (float*)d_out;
    char* ws = (char*)d_ws;

    // layout (peak 128.2 MB):
    // [0]        Ux fp8 16,777,216  (doubles as xb+xbT during prep/attn)
    // [16777216] YpT bf16 10,747,904
    // [27525120] Uw fp8 67,108,864
    // [94633984] Vt bf16 33,554,432 -> end 128,188,416
    bf16* xb     = (bf16*)(ws);
    bf16* xbT    = (bf16*)(ws + 8388608);
    uint8_t* Ux  = (uint8_t*)(ws);
    bf16* YpT    = (bf16*)(ws + 16777216);
    uint8_t* Uw  = (uint8_t*)(ws + 27525120);
    bf16* Vt     = (bf16*)(ws + 94633984);

    hipFuncSetAttribute((const void*)wino_gemm_kernel,
                        hipFuncAttributeMaxDynamicSharedMemorySize, 131072);

    prep_fused_kernel<<<512, 256, 0, stream>>>(x, xb, xbT);
    castw_wino_kernel<<<4096, 256, 0, stream>>>(cw, Uw);
    attn_kernel<<<512, 512, 0, stream>>>(xb, xbT, YpT);
    wino_in_kernel<<<512, 512, 0, stream>>>(YpT, Ux);
    wino_gemm_kernel<<<256, 512, 131072, stream>>>(Ux, Uw, Vt);
    wino_out_kernel<<<2048, 256, 0, stream>>>(Vt, x, cb, out);
}

// Round 16
// 185.491 us; speedup vs baseline: 1.3260x; 1.2372x over previous
//
#include <hip/hip_runtime.h>
#include <stdint.h>

#define BB 32
#define CC 2048
#define NPIX 49
#define KPAD 64

typedef __bf16 bf16;
typedef __bf16 bf16x4 __attribute__((ext_vector_type(4)));
typedef __bf16 bf16x8 __attribute__((ext_vector_type(8)));
typedef float f32x4 __attribute__((ext_vector_type(4)));
typedef uint32_t u32x4 __attribute__((ext_vector_type(4)));
typedef long i64;
typedef long i64x2 __attribute__((ext_vector_type(2)));

#define MFMA(a,b,c) __builtin_amdgcn_mfma_f32_16x16x32_bf16(a,b,c,0,0,0)
#define MFMA8(a,b,c) __builtin_amdgcn_mfma_f32_16x16x32_fp8_fp8(a,b,c,0,0,0)
#define GLOAD_LDS(g, l) __builtin_amdgcn_global_load_lds( \
    (const __attribute__((address_space(1))) void*)(g),   \
    (__attribute__((address_space(3))) void*)(l), 16, 0, 0)

// k-interleave perm of a 4-aligned column index within its 64-block:
// newlocal = lhi*16 + s*8 + (local&7)  (lane lhi's two 8B k-step chunks adjacent)
__device__ __forceinline__ uint32_t kperm(uint32_t c) {
    uint32_t local = c & 63u, s = local >> 5, lh = (local >> 3) & 3u, o8 = local & 7u;
    return (c & ~63u) | (lh * 16u + s * 8u + o8);
}

// ---------- fused prep: x -> xb [B][C][64] AND xbT [B][64][C] ----------
__global__ void prep_fused_kernel(const float* __restrict__ x,
                                  bf16* __restrict__ xb, bf16* __restrict__ xbT) {
    __shared__ float xt[6272];   // 128*49
    const int tid = threadIdx.x;
    const int b = blockIdx.x >> 4, cb = blockIdx.x & 15;
    const float* src = x + ((size_t)(b * 2048 + cb * 128)) * 49;
#pragma unroll
    for (int i = 0; i < 25; i++) {
        int idx = i * 256 + tid;
        if (idx < 6272) xt[idx] = src[idx];
    }
    __syncthreads();
    {
        const int r = tid >> 1, h = tid & 1;
        bf16* dst = xb + ((size_t)(b * 2048 + cb * 128 + r)) * 64 + h * 32;
        const float* row = &xt[r * 49];
#pragma unroll
        for (int v = 0; v < 4; v++) {
            bf16x8 o;
#pragma unroll
            for (int e = 0; e < 8; e++) {
                int n = h * 32 + v * 8 + e;
                o[e] = (bf16)(n < 49 ? row[n] : 0.f);
            }
            *(bf16x8*)(dst + v * 8) = o;
        }
    }
    {
        const int n = tid >> 2, q = tid & 3;
        bf16* dst = xbT + ((size_t)b * 64 + n) * 2048 + cb * 128 + q * 32;
#pragma unroll
        for (int v = 0; v < 4; v++) {
            bf16x8 o;
#pragma unroll
            for (int e = 0; e < 8; e++) {
                int cl = q * 32 + v * 8 + e;
                o[e] = (bf16)(n < 49 ? xt[cl * 49 + n] : 0.f);
            }
            *(bf16x8*)(dst + v * 8) = o;
        }
    }
}

// ---------- Winograd weight transform -> Uw fp8 e4m3 [16][co][kperm(ci)], x16 ----------
__global__ void castw_wino_kernel(const float* __restrict__ cw, uint8_t* __restrict__ Uw) {
    uint32_t t = blockIdx.x * 256u + threadIdx.x;   // 2048*512
    uint32_t q = t & 511u, co = t >> 9;
    uint32_t ci0 = q * 4u;
    uint32_t nci = kperm(ci0);
    const f32x4* src4 = (const f32x4*)(cw + ((size_t)co * 2048u + ci0) * 9u);
    float g[36];
#pragma unroll
    for (int m = 0; m < 9; m++) {
        f32x4 t4 = src4[m];
#pragma unroll
        for (int e = 0; e < 4; e++) g[m * 4 + e] = t4[e];
    }
    float u[16][4];
#pragma unroll
    for (int c4 = 0; c4 < 4; c4++) {
        const float* gg = g + c4 * 9;
        float tr[4][3];
#pragma unroll
        for (int col = 0; col < 3; col++) {
            float a0 = gg[col], a1 = gg[3 + col], a2 = gg[6 + col];
            tr[0][col] = a0;
            tr[1][col] = 0.5f * (a0 + a1 + a2);
            tr[2][col] = 0.5f * (a0 - a1 + a2);
            tr[3][col] = a2;
        }
#pragma unroll
        for (int r = 0; r < 4; r++) {
            u[r * 4 + 0][c4] = tr[r][0];
            u[r * 4 + 1][c4] = 0.5f * (tr[r][0] + tr[r][1] + tr[r][2]);
            u[r * 4 + 2][c4] = 0.5f * (tr[r][0] - tr[r][1] + tr[r][2]);
            u[r * 4 + 3][c4] = tr[r][2];
        }
    }
#pragma unroll
    for (int e = 0; e < 16; e++) {
        int p = __builtin_amdgcn_cvt_pk_fp8_f32(u[e][0] * 16.f, u[e][1] * 16.f, 0, false);
        p = __builtin_amdgcn_cvt_pk_fp8_f32(u[e][2] * 16.f, u[e][3] * 16.f, p, true);
        *(uint32_t*)(Uw + (size_t)e * 4194304u + (size_t)co * 2048u + nci) = (uint32_t)p;
    }
}

// ---------- fused bilinear -> softmax -> Y -> Winograd-in (B^T d B) -> Ux fp8 ----------
// Epilogue computes the input transform straight from Tlds (halo = literal 0);
// YpT is eliminated. Ux scaled x4, columns kperm'd.
__global__ __launch_bounds__(512, 2) void attn_kernel(
    const bf16* __restrict__ xb, const bf16* __restrict__ xbT, uint8_t* __restrict__ Ux)
{
    __shared__ __align__(16) char smem[67584];
    bf16* Ktile = (bf16*)smem;
    bf16* Vtile = (bf16*)(smem + 16384);
    bf16 (*Plds)[16][136] = reinterpret_cast<bf16(*)[16][136]>(smem + 32768);
    bf16 (*Tlds)[132] = reinterpret_cast<bf16(*)[132]>(smem);

    const int tid = threadIdx.x;
    const int w = tid >> 6, l = tid & 63;
    const int lhi = l >> 4, llo = l & 15;
    const uint32_t g = blockIdx.x;
    const int xcd = g & 7, inner = g >> 3;
    const int b = xcd + (inner >> 4) * 8;
    const int cblk = inner & 15;
    const int c0 = cblk * 128 + w * 16;
    const bf16* xbB = xb + (size_t)b * CC * KPAD;
    const bf16* xbTB = xbT + (size_t)b * KPAD * CC;

    bf16x8 aQ[2];
#pragma unroll
    for (int kk = 0; kk < 2; kk++)
        aQ[kk] = *(const bf16x8*)(xbB + (uint32_t)(c0 + llo) * KPAD + kk * 32 + lhi * 8);

    const uint32_t rowK = tid >> 3;
    const uint32_t srcKoff = (uint32_t)(((tid & 7u) ^ (rowK & 7u)) << 3);
    const bf16* kSrc = xbB + (size_t)rowK * KPAD + srcKoff;
    const uint32_t rowV = tid >> 4;
    const uint32_t srcVoff = (uint32_t)(((tid & 15u) ^ (rowV & 7u)) << 3);
    const bf16* vSrc = xbTB + (size_t)rowV * CC + srcVoff;

    f32x4 accY[4];
#pragma unroll
    for (int nf = 0; nf < 4; nf++) accY[nf] = (f32x4){0, 0, 0, 0};
    float rowsum[4] = {};

    const float kES = -0.029442756956917622f;

    for (int dt = 0; dt < 16; dt++) {
        const int d0 = dt * 128;
#pragma unroll
        for (int i = 0; i < 2; i++) {
            GLOAD_LDS(kSrc + (size_t)(d0 + i * 64) * KPAD, (char*)Ktile + i * 8192 + tid * 16);
            GLOAD_LDS(vSrc + d0 + (size_t)i * 32 * CC,     (char*)Vtile + i * 8192 + tid * 16);
        }
        __syncthreads();

        f32x4 accS[8];
#pragma unroll
        for (int df = 0; df < 8; df++) accS[df] = (f32x4){0, 0, 0, 0};
#pragma unroll
        for (int kk = 0; kk < 2; kk++) {
#pragma unroll
            for (int df = 0; df < 8; df++) {
                uint32_t r = (uint32_t)(df * 16 + llo);
                bf16x8 bK = *(const bf16x8*)((const char*)Ktile + r * 128u +
                                             ((((uint32_t)(kk * 4 + lhi)) ^ (r & 7u)) << 4));
                accS[df] = MFMA(aQ[kk], bK, accS[df]);
            }
        }
#pragma unroll
        for (int df = 0; df < 8; df++)
#pragma unroll
            for (int r = 0; r < 4; r++) {
                float p = __builtin_amdgcn_exp2f(accS[df][r] * kES);
                rowsum[r] += p;
                Plds[w][lhi * 4 + r][df * 16 + llo] = (bf16)p;
            }
#pragma unroll
        for (int kk2 = 0; kk2 < 4; kk2++) {
            bf16x8 aP = *(const bf16x8*)&Plds[w][llo][kk2 * 32 + lhi * 8];
#pragma unroll
            for (int nf = 0; nf < 4; nf++) {
                uint32_t r = (uint32_t)(nf * 16 + llo);
                bf16x8 bV = *(const bf16x8*)((const char*)Vtile + r * 256u +
                                             ((((uint32_t)(kk2 * 4 + lhi)) ^ (r & 7u)) << 4));
                accY[nf] = MFMA(aP, bV, accY[nf]);
            }
        }
        __syncthreads();
    }
#pragma unroll
    for (int r = 0; r < 4; r++) {
        float s = rowsum[r];
        s += __shfl_xor(s, 1);
        s += __shfl_xor(s, 2);
        s += __shfl_xor(s, 4);
        s += __shfl_xor(s, 8);
        rowsum[r] = 1.0f / s;
    }
    __syncthreads();   // Tlds aliases K/V tiles
#pragma unroll
    for (int nf = 0; nf < 4; nf++)
#pragma unroll
        for (int r = 0; r < 4; r++) {
            int n = nf * 16 + llo;
            int cl = w * 16 + lhi * 4 + r;
            Tlds[n][cl] = (bf16)(accY[nf][r] * rowsum[r]);
        }
    __syncthreads();

    // ---- fused Winograd input transform: per (tile t, 4-col group) ----
    {
        const int t = tid >> 5;                // 16 tiles
        const int clg = tid & 31;              // 32 col-groups of 4
        const int cl0 = clg * 4;
        const int ti = t >> 2, tj = t & 3;
        float d[4][4][4];
#pragma unroll
        for (int di = 0; di < 4; di++) {
            int i = 2 * ti + di - 1;
#pragma unroll
            for (int dj = 0; dj < 4; dj++) {
                int j = 2 * tj + dj - 1;
                if (i >= 0 && i < 7 && j >= 0 && j < 7) {
                    bf16x4 v = *(const bf16x4*)&Tlds[i * 7 + j][cl0];
#pragma unroll
                    for (int k = 0; k < 4; k++) d[di][dj][k] = (float)v[k];
                } else {
#pragma unroll
                    for (int k = 0; k < 4; k++) d[di][dj][k] = 0.f;
                }
            }
        }
        float R[4][4][4];
#pragma unroll
        for (int dj = 0; dj < 4; dj++)
#pragma unroll
            for (int k = 0; k < 4; k++) {
                R[0][dj][k] = d[0][dj][k] - d[2][dj][k];
                R[1][dj][k] = d[1][dj][k] + d[2][dj][k];
                R[2][dj][k] = d[2][dj][k] - d[1][dj][k];
                R[3][dj][k] = d[1][dj][k] - d[3][dj][k];
            }
        uint32_t nci = kperm((uint32_t)(cblk * 128 + cl0));
        uint8_t* dst = Ux + (size_t)(b * 16 + t) * 2048 + nci;
#pragma unroll
        for (int r = 0; r < 4; r++) {
            float V[4][4];
#pragma unroll
            for (int k = 0; k < 4; k++) {
                V[0][k] = (R[r][0][k] - R[r][2][k]) * 4.f;
                V[1][k] = (R[r][1][k] + R[r][2][k]) * 4.f;
                V[2][k] = (R[r][2][k] - R[r][1][k]) * 4.f;
                V[3][k] = (R[r][1][k] - R[r][3][k]) * 4.f;
            }
#pragma unroll
            for (int cc = 0; cc < 4; cc++) {
                int p = __builtin_amdgcn_cvt_pk_fp8_f32(V[cc][0], V[cc][1], 0, false);
                p = __builtin_amdgcn_cvt_pk_fp8_f32(V[cc][2], V[cc][3], p, true);
                *(uint32_t*)(dst + (size_t)(r * 4 + cc) * 1048576u) = (uint32_t)p;
            }
        }
    }
}

// ---------- Winograd GEMM fp8 (K=2048, K-tile 128): b128 frag reads, R14 offsets ----------
#define CONV_BARRIER() do { __builtin_amdgcn_sched_barrier(0); \
    __builtin_amdgcn_s_barrier(); __builtin_amdgcn_sched_barrier(0); } while (0)
#define CONV_VMW(n) asm volatile("s_waitcnt vmcnt(" #n ")" ::: "memory")

#define WSTAGE(bufOff, t, kh) do {                                             \
    uint32_t kA_ = (uint32_t)(t) * 128u + (uint32_t)(kh) * 64u;                \
    _Pragma("unroll")                                                          \
    for (int i_ = 0; i_ < 2; i_++) {                                           \
        GLOAD_LDS(srcA[i_] + kA_,                                              \
                  smem + (bufOff) + (kh) * 16384 + i_ * 8192 + tid * 16);      \
        GLOAD_LDS(srcB[i_] + kA_,                                              \
                  smem + (bufOff) + 32768 + (kh) * 16384 + i_ * 8192 + tid * 16); \
    }                                                                          \
} while (0)

#define CONV_PHASE(bufOff, kk, GATE, STAGE_STMT) do {                          \
    CONV_VMW(GATE);                                                            \
    CONV_BARRIER();                                                            \
    i64x2 af[8], bfr[4];                                                       \
    _Pragma("unroll")                                                          \
    for (int f = 0; f < 8; f++)                                                \
        af[f] = *(const i64x2*)(smem + (bufOff) + (kk) * 16384 + offA[f]);     \
    _Pragma("unroll")                                                          \
    for (int f = 0; f < 4; f++)                                                \
        bfr[f] = *(const i64x2*)(smem + (bufOff) + 32768 + (kk) * 16384 + offB[f]); \
    STAGE_STMT;                                                                \
    asm volatile("s_waitcnt lgkmcnt(0)" ::: "memory");                         \
    __builtin_amdgcn_sched_barrier(0);                                         \
    __builtin_amdgcn_s_setprio(1);                                             \
    _Pragma("unroll")                                                          \
    for (int s = 0; s < 2; s++)                                                \
        _Pragma("unroll")                                                      \
        for (int fm = 0; fm < 8; fm++)                                         \
            _Pragma("unroll")                                                  \
            for (int fn = 0; fn < 4; fn++)                                     \
                acc[fm][fn] = MFMA8(af[fm][s], bfr[fn][s], acc[fm][fn]);       \
    __builtin_amdgcn_s_setprio(0);                                             \
    __builtin_amdgcn_sched_barrier(0);                                         \
} while (0)

__global__ __launch_bounds__(512, 2) void wino_gemm_kernel(
    const uint8_t* __restrict__ Ux, const uint8_t* __restrict__ Uw, bf16* __restrict__ Vt)
{
    extern __shared__ __align__(16) char smem[];
    const int tid = threadIdx.x;
    const int w = tid >> 6, l = tid & 63;
    const int lhi = l >> 4, llo = l & 15;
    const int wm = w >> 2, wn = w & 3;           // wave owns 128 n x 64 co

    uint32_t g = blockIdx.x;
    uint32_t xcd = g & 7u, inner = g >> 3;       // [0,32)
    uint32_t e = xcd * 2u + (inner >> 4);        // 2 e-planes per XCD
    uint32_t sub = inner & 15u;
    uint32_t mt = sub >> 3, nt = sub & 7u;

    uint32_t rowLoc = tid >> 2;                  // [0,128)
    uint32_t slot = tid & 3u;
    const uint8_t* srcA[2];
    const uint8_t* srcB[2];
#pragma unroll
    for (int i = 0; i < 2; i++) {
        uint32_t row = (uint32_t)i * 128u + rowLoc;
        uint32_t swz = (uint32_t)((slot ^ ((row >> 1) & 3u)) << 4);   // bytes
        srcA[i] = Ux + (size_t)e * 1048576u + (size_t)(mt * 256u + row) * 2048u + swz;
        srcB[i] = Uw + (size_t)e * 4194304u + (size_t)(nt * 256u + row) * 2048u + swz;
    }

    // b128 frag offsets (R14 formula; k-interleaved layout makes 16B = both k-steps)
    uint32_t offA[8], offB[4];
#pragma unroll
    for (int f = 0; f < 8; f++) {
        uint32_t r = (uint32_t)(wm * 128 + f * 16 + llo);
        offA[f] = r * 64u + (uint32_t)(((uint32_t)lhi ^ ((r >> 1) & 3u)) << 4);
    }
#pragma unroll
    for (int f = 0; f < 4; f++) {
        uint32_t r = (uint32_t)(wn * 64 + f * 16 + llo);
        offB[f] = r * 64u + (uint32_t)(((uint32_t)lhi ^ ((r >> 1) & 3u)) << 4);
    }

    f32x4 acc[8][4];
#pragma unroll
    for (int fm = 0; fm < 8; fm++)
#pragma unroll
        for (int fn = 0; fn < 4; fn++) acc[fm][fn] = (f32x4){0, 0, 0, 0};

    // prologue: T0.k0, T0.k1 -> buf0; T1.k0 -> buf1
    WSTAGE(0, 0, 0);
    WSTAGE(0, 0, 1);
    WSTAGE(65536, 1, 0);

    for (int it = 0; it < 7; ++it) {
        const int t0 = it * 2;
        CONV_PHASE(0,     0, 8, WSTAGE(65536, t0 + 1, 1));
        CONV_PHASE(0,     1, 8, WSTAGE(0,     t0 + 2, 0));
        CONV_PHASE(65536, 0, 8, WSTAGE(0,     t0 + 2, 1));
        CONV_PHASE(65536, 1, 8, WSTAGE(65536, t0 + 3, 0));
    }
    // peeled final pair (tiles 14 buf0, 15 buf1); gates 8,8,4,0
    CONV_PHASE(0,     0, 8, WSTAGE(65536, 15, 1));
    CONV_PHASE(0,     1, 8, (void)0);
    CONV_PHASE(65536, 0, 4, (void)0);
    CONV_PHASE(65536, 1, 0, (void)0);

    bf16* pz = Vt + (size_t)e * 1048576u;
    uint32_t n0 = mt * 256u + (uint32_t)(wm * 128 + lhi * 4);
    uint32_t co0 = nt * 256u + (uint32_t)(wn * 64 + llo);
#pragma unroll
    for (int fm = 0; fm < 8; fm++)
#pragma unroll
        for (int fn = 0; fn < 4; fn++)
#pragma unroll
            for (int r = 0; r < 4; r++)
                pz[(size_t)(n0 + fm * 16u + r) * 2048u + (co0 + fn * 16u)] =
                    (bf16)acc[fm][fn][r];
}

// ---------- Winograd output transform + bias + residual (M scaled by 1/64) ----------
__global__ void wino_out_kernel(const bf16* __restrict__ Vt, const float* __restrict__ x,
                                const float* __restrict__ cb, float* __restrict__ out)
{
    __shared__ float Ml[16][16][33];
    __shared__ float Ol[32][50];
    __shared__ float cbl[32];
    const int tid = threadIdx.x;
    const int b = blockIdx.x >> 6, cg = blockIdx.x & 63;
    const int c0 = cg * 32;

    {
        int e = tid >> 4, t = tid & 15;
        const bf16* src = Vt + ((size_t)e * 512 + b * 16 + t) * 2048 + c0;
#pragma unroll
        for (int v = 0; v < 4; v++) {
            bf16x8 vv = *(const bf16x8*)(src + v * 8);
#pragma unroll
            for (int k = 0; k < 8; k++) Ml[e][t][v * 8 + k] = (float)vv[k] * 0.015625f;
        }
    }
    if (tid < 32) cbl[tid] = cb[c0 + tid];
    __syncthreads();

    {
        int t = tid & 15, cp = tid >> 4;
        int ti = t >> 2, tj = t & 3;
#pragma unroll
        for (int cc2 = 0; cc2 < 2; cc2++) {
            int cc = cp * 2 + cc2;
            float M[16];
#pragma unroll
            for (int e = 0; e < 16; e++) M[e] = Ml[e][t][cc];
            float s0[4], s1[4];
#pragma unroll
            for (int col = 0; col < 4; col++) {
                s0[col] = M[col] + M[4 + col] + M[8 + col];
                s1[col] = M[4 + col] - M[8 + col] - M[12 + col];
            }
            float y00 = s0[0] + s0[1] + s0[2];
            float y01 = s0[1] - s0[2] - s0[3];
            float y10 = s1[0] + s1[1] + s1[2];
            float y11 = s1[1] - s1[2] - s1[3];
            int i0 = 2 * ti, j0 = 2 * tj;
            Ol[cc][i0 * 7 + j0] = y00;
            if (j0 + 1 < 7) Ol[cc][i0 * 7 + j0 + 1] = y01;
            if (i0 + 1 < 7) Ol[cc][(i0 + 1) * 7 + j0] = y10;
            if (i0 + 1 < 7 && j0 + 1 < 7) Ol[cc][(i0 + 1) * 7 + j0 + 1] = y11;
        }
    }
    __syncthreads();

    {
        const float* xs = x + ((size_t)b * 2048 + c0) * 49;
        float* os = out + ((size_t)b * 2048 + c0) * 49;
        for (int k = tid; k < 1568; k += 256) {
            int c = k / 49, p = k - c * 49;
            os[k] = Ol[c][p] + cbl[c] + xs[k];
        }
    }
}

extern "C" void kernel_launch(void* const* d_in, const int* in_sizes, int n_in,
                              void* d_out, int out_size, void* d_ws, size_t ws_size,
                              hipStream_t stream) {
    (void)in_sizes; (void)n_in; (void)out_size; (void)ws_size;
    const float* x = (const float*)d_in[0];
    const float* cw = (const float*)d_in[1];
    const float* cb = (const float*)d_in[2];
    float* out = (float*)d_out;
    char* ws = (char*)d_ws;

    // layout (peak 134.2 MB):
    // [0]         xb  8,388,608
    // [8388608]   xbT 8,388,608
    // [16777216]  Ux fp8 16,777,216
    // [33554432]  Uw fp8 67,108,864
    // [100663296] Vt bf16 33,554,432  -> end 134,217,728
    bf16* xb     = (bf16*)(ws);
    bf16* xbT    = (bf16*)(ws + 8388608);
    uint8_t* Ux  = (uint8_t*)(ws + 16777216);
    uint8_t* Uw  = (uint8_t*)(ws + 33554432);
    bf16* Vt     = (bf16*)(ws + 100663296);

    hipFuncSetAttribute((const void*)wino_gemm_kernel,
                        hipFuncAttributeMaxDynamicSharedMemorySize, 131072);

    prep_fused_kernel<<<512, 256, 0, stream>>>(x, xb, xbT);
    castw_wino_kernel<<<4096, 256, 0, stream>>>(cw, Uw);
    attn_kernel<<<512, 512, 0, stream>>>(xb, xbT, Ux);
    wino_gemm_kernel<<<256, 512, 131072, stream>>>(Ux, Uw, Vt);
    wino_out_kernel<<<2048, 256, 0, stream>>>(Vt, x, cb, out);
}